// Round 7
// baseline (84.897 us; speedup 1.0000x reference)
//
#include <hip/hip_runtime.h>

#define BATCH  4096
#define TLEN   750
#define NK     6               // pair offsets k=1..6 (k=0 contributes exactly 0)
#define LPW    60              // lanes owning columns per wave
#define CPL    2               // columns per lane (float2)
#define OWN    (LPW*CPL)       // 120 owned columns per wave
#define NSTRIP 7               // 7*120 = 840 >= 750
#define WPB    4               // waves per block
#define NTH    256
#define NGR    64              // row-groups (must be pow2 for the &63 rendezvous)
#define RPB    (BATCH/NGR)     // 64 rows per block
#define RPW    (RPB/WPB)       // 16 rows per wave
#define QSZ    (2*NK*128)      // 1536 floats per (strip,group)
#define TP     752             // pitch of T rows (i-index)

// ---------------- helpers ----------------

template<int NW>
__device__ __forceinline__ float block_reduce(float v, float* red) {
    #pragma unroll
    for (int off = 32; off > 0; off >>= 1) v += __shfl_down(v, off, 64);
    const int t = threadIdx.x;
    if ((t & 63) == 0) red[t >> 6] = v;
    __syncthreads();
    float r = 0.f;
    if (t == 0) {
        #pragma unroll
        for (int w = 0; w < NW; ++w) r += red[w];
    }
    __syncthreads();
    return r;
}

__device__ __forceinline__ float2 shfl_down2(float2 v, int d) {
    float2 r;
    r.x = __shfl_down(v.x, d, 64);
    r.y = __shfl_down(v.y, d, 64);
    return r;
}

// ---------------- fused kernel ----------------
// Phase A: (strip, group) pair partials (round-6 K1 body).
// Phase B: per-strip last block reduces the strip's 64 partials.
// Phase C: globally-last strip reducer finishes (exp, map, res, out).
// Counters use modulo arithmetic -> no reset needed across graph replays.
__global__ __launch_bounds__(NTH) void actloss_fused(
        const float* __restrict__ a, const float* __restrict__ a2,
        float* __restrict__ p, float* __restrict__ sf,
        float* __restrict__ resp, float* __restrict__ sres,
        unsigned* __restrict__ sctr, unsigned* __restrict__ gctr,
        float* __restrict__ out) {
    const int t = threadIdx.x;
    const int w = t >> 6;
    const int l = t & 63;
    const int s = (int)(blockIdx.x % NSTRIP);
    const int g = (int)(blockIdx.x / NSTRIP);

    // ---- phase A ----
    const int colr = s * OWN + 2 * l;                       // even
    const int col  = colr <= TLEN - 2 ? colr : TLEN - 2;    // clamp, keep 8B align
    const bool own = (l < LPW) && (colr < TLEN);

    float s1[CPL][NK], s2[CPL][NK];
    #pragma unroll
    for (int c = 0; c < CPL; ++c)
        #pragma unroll
        for (int k = 0; k < NK; ++k) { s1[c][k] = 0.f; s2[c][k] = 0.f; }
    float res = 0.f;

    const int b0 = g * RPB + w * RPW;
    #pragma unroll 4
    for (int r = 0; r < RPW; ++r) {
        const size_t off = (size_t)(b0 + r) * TLEN + col;
        const float2 av = *reinterpret_cast<const float2*>(a + off);
        const float2 bv = *reinterpret_cast<const float2*>(a2 + off);
        const float2 a1 = shfl_down2(av, 1), a2v = shfl_down2(av, 2), a3v = shfl_down2(av, 3);
        const float2 b1 = shfl_down2(bv, 1), b2v = shfl_down2(bv, 2), b3v = shfl_down2(bv, 3);
        const float n[8] = {av.x, av.y, a1.x, a1.y, a2v.x, a2v.y, a3v.x, a3v.y};
        const float m[8] = {bv.x, bv.y, b1.x, b1.y, b2v.x, b2v.y, b3v.x, b3v.y};
        #pragma unroll
        for (int k = 1; k <= NK; ++k) {
            const float d0 = n[0] - n[k];
            s1[0][k - 1] = fmaf(d0, d0, s1[0][k - 1]);
            s2[0][k - 1] += fabsf(m[0] - m[k]);
            const float d1 = n[1] - n[1 + k];
            s1[1][k - 1] = fmaf(d1, d1, s1[1][k - 1]);
            s2[1][k - 1] += fabsf(m[1] - m[1 + k]);
        }
        if (own) {
            const float r0 = av.x - bv.x;
            const float r1 = av.y - bv.y;
            res = fmaf(r0, r0, res);
            res = fmaf(r1, r1, res);
        }
    }

    // cross-wave reduce in LDS -> one 1536-float partial per block
    __shared__ float lds[WPB][QSZ];
    __shared__ float rw[WPB];
    #pragma unroll
    for (int k = 0; k < NK; ++k) {
        lds[w][k * 128 + 2 * l]                = s1[0][k];
        lds[w][k * 128 + 2 * l + 1]            = s1[1][k];
        lds[w][NK * 128 + k * 128 + 2 * l]     = s2[0][k];
        lds[w][NK * 128 + k * 128 + 2 * l + 1] = s2[1][k];
    }
    #pragma unroll
    for (int off = 32; off > 0; off >>= 1) res += __shfl_down(res, off, 64);
    if (l == 0) rw[w] = res;
    __syncthreads();

    float* pg = p + ((size_t)s * NGR + g) * QSZ;
    for (int q = t; q < QSZ; q += NTH)
        pg[q] = (lds[0][q] + lds[1][q]) + (lds[2][q] + lds[3][q]);
    if (t == 0) resp[s * NGR + g] = (rw[0] + rw[1]) + (rw[2] + rw[3]);

    // ---- strip rendezvous ----
    __threadfence();
    __syncthreads();
    __shared__ unsigned lastS;
    if (t == 0) lastS = ((atomicAdd(&sctr[s], 1u) & (NGR - 1)) == NGR - 1) ? 1u : 0u;
    __syncthreads();
    if (!lastS) return;
    __threadfence();   // acquire: see all of this strip's p/resp stores

    // ---- phase B: strip reduce (coalesced; 6 slots/thread x 64 groups) ----
    const float* ps = p + (size_t)s * NGR * QSZ;
    #pragma unroll
    for (int q0 = 0; q0 < QSZ; q0 += NTH) {
        float sum = 0.f;
        #pragma unroll 8
        for (int g2 = 0; g2 < NGR; ++g2) sum += ps[(size_t)g2 * QSZ + q0 + t];
        sf[s * QSZ + q0 + t] = sum;
    }
    {
        float rr = (t < NGR) ? resp[s * NGR + t] : 0.f;
        __shared__ float red2[4];
        const float rsum = block_reduce<4>(rr, red2);
        if (t == 0) sres[s] = rsum;
    }

    // ---- global rendezvous ----
    __threadfence();
    __syncthreads();
    __shared__ unsigned lastG;
    if (t == 0) lastG = ((atomicAdd(gctr, 1u) % NSTRIP) == NSTRIP - 1) ? 1u : 0u;
    __syncthreads();
    if (!lastG) return;
    __threadfence();   // acquire: see all strips' sf/sres stores

    // ---- phase C: finish ----
    __shared__ float Tl[NK * TP];   // ~18 KB
    for (int e = t; e < NSTRIP * LPW * CPL * NK; e += NTH) {   // 5040
        const int k = e % NK + 1;
        int u = e / NK;
        const int c = u % CPL; u /= CPL;
        const int ll = u % LPW;
        const int ss = u / LPW;
        const int i = ss * OWN + 2 * ll + c;
        if (i + k <= TLEN - 1) {
            const int sl = ss * QSZ + (k - 1) * 128 + 2 * ll + c;
            Tl[(k - 1) * TP + i] = expf(-0.5f * sf[sl]) * sf[sl + NK * 128];
        }
    }
    __syncthreads();

    float acc = 0.f;
    for (int idx = t; idx < TLEN * 11; idx += NTH) {
        const int i = idx / 11, j = idx - i * 11;
        int c = i + j - 6;
        c = c < 0 ? 0 : (c > TLEN - 1 ? TLEN - 1 : c);
        const int k = i < c ? c - i : i - c;
        if (k > 0) acc += Tl[(k - 1) * TP + (i < c ? i : c)];
    }
    float racc = (t < NSTRIP) ? sres[t] : 0.f;

    __shared__ float red3[4];
    const float accR  = block_reduce<4>(acc, red3);
    const float raccR = block_reduce<4>(racc, red3);
    if (t == 0) out[0] = (accR + 0.1f * raccR) * (1.0f / (float)BATCH);
}

// ---------------- fallback slow path (round-1, known-good) ----------------

__global__ __launch_bounds__(256) void actloss_col_kernel(
        const float* __restrict__ a, const float* __restrict__ a2,
        float* __restrict__ part) {
    const int i = blockIdx.x;
    const int t = threadIdx.x;
    __shared__ float red[4];
    int cidx[11];
    #pragma unroll
    for (int j = 0; j < 11; ++j) {
        int c = i + j - 6;
        cidx[j] = c < 0 ? 0 : (c > TLEN - 1 ? TLEN - 1 : c);
    }
    float s1[11], s2[11];
    #pragma unroll
    for (int j = 0; j < 11; ++j) { s1[j] = 0.f; s2[j] = 0.f; }
    float resacc = 0.f;
    for (int b = t; b < BATCH; b += 256) {
        const float* arow  = a  + (size_t)b * TLEN;
        const float* a2row = a2 + (size_t)b * TLEN;
        const float ai = arow[i], a2i = a2row[i];
        const float r = ai - a2i;
        resacc = fmaf(r, r, resacc);
        #pragma unroll
        for (int j = 0; j < 11; ++j) {
            const float d = ai - arow[cidx[j]];
            s1[j] = fmaf(d, d, s1[j]);
            s2[j] += fabsf(a2i - a2row[cidx[j]]);
        }
    }
    float term = 0.f;
    #pragma unroll
    for (int j = 0; j < 11; ++j) {
        const float s1r = block_reduce<4>(s1[j], red);
        const float s2r = block_reduce<4>(s2[j], red);
        if (t == 0) term += expf(-0.5f * s1r) * s2r;
    }
    const float resr = block_reduce<4>(resacc, red);
    if (t == 0) part[i] = (term + 0.1f * resr) * (1.0f / (float)BATCH);
}

__global__ __launch_bounds__(256) void actloss_fallback_reduce(
        const float* __restrict__ part, float* __restrict__ out) {
    __shared__ float red[4];
    float v = 0.f;
    for (int k = threadIdx.x; k < TLEN; k += 256) v += part[k];
    const float r = block_reduce<4>(v, red);
    if (threadIdx.x == 0) out[0] = r;
}

// ---------------- launcher ----------------

extern "C" void kernel_launch(void* const* d_in, const int* in_sizes, int n_in,
                              void* d_out, int out_size, void* d_ws, size_t ws_size,
                              hipStream_t stream) {
    const float* a  = (const float*)d_in[0];   // actioness
    const float* a2 = (const float*)d_in[1];   // actioness_2
    float* out = (float*)d_out;
    float* ws  = (float*)d_ws;

    const size_t pN   = (size_t)NSTRIP * NGR * QSZ;   // 688128
    const size_t sfN  = (size_t)NSTRIP * QSZ;         // 10752
    const size_t rpN  = (size_t)NSTRIP * NGR;         // 448
    const size_t need = (pN + sfN + rpN + 8 + 8 + 8) * sizeof(float);

    if (ws_size >= need) {
        float*    p    = ws;
        float*    sf   = p + pN;
        float*    resp = sf + sfN;
        float*    sres = resp + rpN;        // 7 (padded to 8)
        unsigned* sctr = (unsigned*)(sres + 8);   // 7 (padded to 8)
        unsigned* gctr = sctr + 8;
        actloss_fused<<<NSTRIP * NGR, NTH, 0, stream>>>(
            a, a2, p, sf, resp, sres, sctr, gctr, out);
    } else {
        float* part = ws;   // 750 floats
        actloss_col_kernel<<<TLEN, 256, 0, stream>>>(a, a2, part);
        actloss_fallback_reduce<<<1, 256, 0, stream>>>(part, out);
    }
}

// Round 8
// 33.285 us; speedup vs baseline: 2.5506x; 2.5506x over previous
//
#include <hip/hip_runtime.h>

#define BATCH  4096
#define TLEN   750
#define NK     6               // pair offsets k=1..6 (k=0 contributes exactly 0)
#define LPW    60              // lanes owning columns per wave
#define CPL    2               // columns per lane (float2)
#define OWN    (LPW*CPL)       // 120 owned columns per wave
#define NSTRIP 7               // 7*120 = 840 >= 750
#define WPB    4               // waves per block
#define NTH    256
#define NGR    128             // row-groups
#define RPB    (BATCH/NGR)     // 32 rows per block
#define RPW    (RPB/WPB)       // 8 rows per wave
#define QSZ    (2*NK*128)      // 1536 floats per (strip,group)
#define SLOTS  (NSTRIP*QSZ)    // 10752 = 42*256
#define K2GRID (SLOTS/256)     // 42
#define TP     752             // pitch of T rows (i-index)

// ---------------- helpers ----------------

template<int NW>
__device__ __forceinline__ float block_reduce(float v, float* red) {
    #pragma unroll
    for (int off = 32; off > 0; off >>= 1) v += __shfl_down(v, off, 64);
    const int t = threadIdx.x;
    if ((t & 63) == 0) red[t >> 6] = v;
    __syncthreads();
    float r = 0.f;
    if (t == 0) {
        #pragma unroll
        for (int w = 0; w < NW; ++w) r += red[w];
    }
    __syncthreads();
    return r;
}

__device__ __forceinline__ float2 shfl_down2(float2 v, int d) {
    float2 r;
    r.x = __shfl_down(v.x, d, 64);
    r.y = __shfl_down(v.y, d, 64);
    return r;
}

// ---------------- K1: strip x row-group pair partials ----------------
// Lane owns 2 columns (float2); neighbors k=1..6 via 3 float2 shuffles per array.
// Lanes 60..63 are halo; clamped/garbage slots are finite and never consumed.
__global__ __launch_bounds__(NTH) void actloss_k1(
        const float* __restrict__ a, const float* __restrict__ a2,
        float* __restrict__ p, float* __restrict__ resp) {
    const int t = threadIdx.x;
    const int w = t >> 6;
    const int l = t & 63;
    const int s = (int)(blockIdx.x % NSTRIP);
    const int g = (int)(blockIdx.x / NSTRIP);

    const int colr = s * OWN + 2 * l;                       // even
    const int col  = colr <= TLEN - 2 ? colr : TLEN - 2;    // clamp, keep 8B align
    const bool own = (l < LPW) && (colr < TLEN);

    float s1[CPL][NK], s2[CPL][NK];
    #pragma unroll
    for (int c = 0; c < CPL; ++c)
        #pragma unroll
        for (int k = 0; k < NK; ++k) { s1[c][k] = 0.f; s2[c][k] = 0.f; }
    float res = 0.f;

    const int b0 = g * RPB + w * RPW;
    #pragma unroll
    for (int r = 0; r < RPW; ++r) {
        const size_t off = (size_t)(b0 + r) * TLEN + col;
        const float2 av = *reinterpret_cast<const float2*>(a + off);
        const float2 bv = *reinterpret_cast<const float2*>(a2 + off);
        const float2 a1 = shfl_down2(av, 1), a2v = shfl_down2(av, 2), a3v = shfl_down2(av, 3);
        const float2 b1 = shfl_down2(bv, 1), b2v = shfl_down2(bv, 2), b3v = shfl_down2(bv, 3);
        const float n[8] = {av.x, av.y, a1.x, a1.y, a2v.x, a2v.y, a3v.x, a3v.y};
        const float m[8] = {bv.x, bv.y, b1.x, b1.y, b2v.x, b2v.y, b3v.x, b3v.y};
        #pragma unroll
        for (int k = 1; k <= NK; ++k) {
            const float d0 = n[0] - n[k];
            s1[0][k - 1] = fmaf(d0, d0, s1[0][k - 1]);
            s2[0][k - 1] += fabsf(m[0] - m[k]);
            const float d1 = n[1] - n[1 + k];
            s1[1][k - 1] = fmaf(d1, d1, s1[1][k - 1]);
            s2[1][k - 1] += fabsf(m[1] - m[1 + k]);
        }
        if (own) {
            const float r0 = av.x - bv.x;
            const float r1 = av.y - bv.y;
            res = fmaf(r0, r0, res);
            res = fmaf(r1, r1, res);
        }
    }

    // cross-wave reduce in LDS -> one 1536-float partial per block
    __shared__ float lds[WPB][QSZ];
    __shared__ float rw[WPB];
    #pragma unroll
    for (int k = 0; k < NK; ++k) {
        lds[w][k * 128 + 2 * l]                = s1[0][k];
        lds[w][k * 128 + 2 * l + 1]            = s1[1][k];
        lds[w][NK * 128 + k * 128 + 2 * l]     = s2[0][k];
        lds[w][NK * 128 + k * 128 + 2 * l + 1] = s2[1][k];
    }
    #pragma unroll
    for (int off = 32; off > 0; off >>= 1) res += __shfl_down(res, off, 64);
    if (l == 0) rw[w] = res;
    __syncthreads();

    // layout: p[g*SLOTS + s*QSZ + q] so K2 strides by SLOTS
    float* pg = p + (size_t)g * SLOTS + (size_t)s * QSZ;
    for (int q = t; q < QSZ; q += NTH)
        pg[q] = (lds[0][q] + lds[1][q]) + (lds[2][q] + lds[3][q]);
    if (t == 0) resp[blockIdx.x] = (rw[0] + rw[1]) + (rw[2] + rw[3]);
}

// ---------------- K2: final slot sums (no fence, no finish) ----------------
__global__ __launch_bounds__(256) void actloss_k2(
        const float* __restrict__ p, float* __restrict__ fin) {
    const int slot = (int)blockIdx.x * 256 + threadIdx.x;  // always < SLOTS
    float sum = 0.f;
    #pragma unroll 8
    for (int g = 0; g < NGR; ++g) sum += p[(size_t)g * SLOTS + slot];
    fin[slot] = sum;
}

// ---------------- K3: one-block finish ----------------
__global__ __launch_bounds__(256) void actloss_k3(
        const float* __restrict__ fin, const float* __restrict__ resp,
        float* __restrict__ out) {
    const int t = threadIdx.x;
    __shared__ float sm[SLOTS];      // ~43 KB
    __shared__ float Tl[NK * TP];    // ~18 KB
    for (int q = t; q < SLOTS; q += 256) sm[q] = fin[q];
    __syncthreads();

    // T[k][i] = exp(-0.5*S1)*S2 for valid pairs (i, i+k), i+k <= 749
    for (int e = t; e < NSTRIP * LPW * CPL * NK; e += 256) {   // 5040
        const int k = e % NK + 1;
        int u = e / NK;
        const int c = u % CPL; u /= CPL;
        const int ll = u % LPW;
        const int ss = u / LPW;
        const int i = ss * OWN + 2 * ll + c;
        if (i + k <= TLEN - 1) {
            const int sl = ss * QSZ + (k - 1) * 128 + 2 * ll + c;
            Tl[(k - 1) * TP + i] = expf(-0.5f * sm[sl]) * sm[sl + NK * 128];
        }
    }
    __syncthreads();

    // map the 8250 (i,j) window terms onto pairs
    float acc = 0.f;
    for (int idx = t; idx < TLEN * 11; idx += 256) {
        const int i = idx / 11, j = idx - i * 11;
        int c = i + j - 6;
        c = c < 0 ? 0 : (c > TLEN - 1 ? TLEN - 1 : c);
        const int k = i < c ? c - i : i - c;
        if (k > 0) acc += Tl[(k - 1) * TP + (i < c ? i : c)];
    }
    float racc = 0.f;
    for (int q = t; q < NSTRIP * NGR; q += 256) racc += resp[q];

    __shared__ float red[4];
    const float accR  = block_reduce<4>(acc, red);
    const float raccR = block_reduce<4>(racc, red);
    if (t == 0) out[0] = (accR + 0.1f * raccR) * (1.0f / (float)BATCH);
}

// ---------------- fallback slow path (round-1, known-good) ----------------

__global__ __launch_bounds__(256) void actloss_col_kernel(
        const float* __restrict__ a, const float* __restrict__ a2,
        float* __restrict__ part) {
    const int i = blockIdx.x;
    const int t = threadIdx.x;
    __shared__ float red[4];
    int cidx[11];
    #pragma unroll
    for (int j = 0; j < 11; ++j) {
        int c = i + j - 6;
        cidx[j] = c < 0 ? 0 : (c > TLEN - 1 ? TLEN - 1 : c);
    }
    float s1[11], s2[11];
    #pragma unroll
    for (int j = 0; j < 11; ++j) { s1[j] = 0.f; s2[j] = 0.f; }
    float resacc = 0.f;
    for (int b = t; b < BATCH; b += 256) {
        const float* arow  = a  + (size_t)b * TLEN;
        const float* a2row = a2 + (size_t)b * TLEN;
        const float ai = arow[i], a2i = a2row[i];
        const float r = ai - a2i;
        resacc = fmaf(r, r, resacc);
        #pragma unroll
        for (int j = 0; j < 11; ++j) {
            const float d = ai - arow[cidx[j]];
            s1[j] = fmaf(d, d, s1[j]);
            s2[j] += fabsf(a2i - a2row[cidx[j]]);
        }
    }
    float term = 0.f;
    #pragma unroll
    for (int j = 0; j < 11; ++j) {
        const float s1r = block_reduce<4>(s1[j], red);
        const float s2r = block_reduce<4>(s2[j], red);
        if (t == 0) term += expf(-0.5f * s1r) * s2r;
    }
    const float resr = block_reduce<4>(resacc, red);
    if (t == 0) part[i] = (term + 0.1f * resr) * (1.0f / (float)BATCH);
}

__global__ __launch_bounds__(256) void actloss_fallback_reduce(
        const float* __restrict__ part, float* __restrict__ out) {
    __shared__ float red[4];
    float v = 0.f;
    for (int k = threadIdx.x; k < TLEN; k += 256) v += part[k];
    const float r = block_reduce<4>(v, red);
    if (threadIdx.x == 0) out[0] = r;
}

// ---------------- launcher ----------------

extern "C" void kernel_launch(void* const* d_in, const int* in_sizes, int n_in,
                              void* d_out, int out_size, void* d_ws, size_t ws_size,
                              hipStream_t stream) {
    const float* a  = (const float*)d_in[0];   // actioness
    const float* a2 = (const float*)d_in[1];   // actioness_2
    float* out = (float*)d_out;
    float* ws  = (float*)d_ws;

    const size_t pN  = (size_t)NGR * SLOTS;       // 1,376,256 floats
    const size_t need = (pN + SLOTS + (size_t)NSTRIP * NGR + 16) * sizeof(float);

    if (ws_size >= need) {
        float* p    = ws;
        float* fin  = p + pN;
        float* resp = fin + SLOTS;
        actloss_k1<<<NSTRIP * NGR, NTH, 0, stream>>>(a, a2, p, resp);
        actloss_k2<<<K2GRID, 256, 0, stream>>>(p, fin);
        actloss_k3<<<1, 256, 0, stream>>>(fin, resp, out);
    } else {
        float* part = ws;   // 750 floats
        actloss_col_kernel<<<TLEN, 256, 0, stream>>>(a, a2, part);
        actloss_fallback_reduce<<<1, 256, 0, stream>>>(part, out);
    }
}

// Round 9
// 30.790 us; speedup vs baseline: 2.7573x; 1.0810x over previous
//
#include <hip/hip_runtime.h>

#define BATCH  4096
#define TLEN   750
#define NK     6                 // pair offsets k=1..6 (k=0 contributes exactly 0)
#define WSTRIP 250               // owned columns per strip
#define NSTRIP 3                 // 3*250 = 750 exactly
#define NTH1   512               // K1 block size (8 waves)
#define WPB    8
#define NGR    128               // row-groups
#define RPB    (BATCH/NGR)       // 32 rows per block
#define RPW    (RPB/WPB)         // 4 rows per wave
#define QSZ    (2*NK*256)        // 3072 floats per (strip,group) partial
#define SLOTS  (NSTRIP*QSZ)      // 9216 = 36*256
#define K2GRID (SLOTS/256)       // 36
#define TP     752               // pitch of T rows (i-index)

// ---------------- helpers ----------------

template<int NW>
__device__ __forceinline__ float block_reduce(float v, float* red) {
    #pragma unroll
    for (int off = 32; off > 0; off >>= 1) v += __shfl_down(v, off, 64);
    const int t = threadIdx.x;
    if ((t & 63) == 0) red[t >> 6] = v;
    __syncthreads();
    float r = 0.f;
    if (t == 0) {
        #pragma unroll
        for (int w = 0; w < NW; ++w) r += red[w];
    }
    __syncthreads();
    return r;
}

// ---------------- K1: strip x row-group pair partials ----------------
// Lane owns 4 columns (colr..colr+3) via two float2 loads (bases always even ->
// 8B aligned; min(...,748) clamp keeps the last row in-bounds). Neighborhood
// n[0..9] = cols colr..colr+9: n[4..7] from lane+1 (4 shuffles), n[8..9] from
// lane+2 (2 shuffles). Clamped/garbage values only reach slots with q>=250 or
// i+k>749, which the finish kernel provably never reads.
__global__ __launch_bounds__(NTH1, 3) void actloss_k1(
        const float* __restrict__ a, const float* __restrict__ a2,
        float* __restrict__ p, float* __restrict__ resp) {
    const int t = threadIdx.x;
    const int w = t >> 6;
    const int l = t & 63;
    const int s = (int)(blockIdx.x % NSTRIP);
    const int g = (int)(blockIdx.x / NSTRIP);

    const int colr = s * WSTRIP + 4 * l;
    const int bc0  = min(colr,     748);   // base of cols (colr, colr+1)
    const int bc1  = min(colr + 2, 748);   // base of cols (colr+2, colr+3)

    float maskf[4];
    #pragma unroll
    for (int c = 0; c < 4; ++c) maskf[c] = (4 * l + c < WSTRIP) ? 1.f : 0.f;

    float s1[4][NK], s2[4][NK];
    #pragma unroll
    for (int c = 0; c < 4; ++c)
        #pragma unroll
        for (int k = 0; k < NK; ++k) { s1[c][k] = 0.f; s2[c][k] = 0.f; }
    float res = 0.f;

    const int r0 = g * RPB + w * RPW;
    #pragma unroll
    for (int r = 0; r < RPW; ++r) {
        const size_t off = (size_t)(r0 + r) * TLEN;
        const float2 av0 = *reinterpret_cast<const float2*>(a  + off + bc0);
        const float2 av1 = *reinterpret_cast<const float2*>(a  + off + bc1);
        const float2 bv0 = *reinterpret_cast<const float2*>(a2 + off + bc0);
        const float2 bv1 = *reinterpret_cast<const float2*>(a2 + off + bc1);

        float n[10], m[10];
        n[0] = av0.x; n[1] = av0.y; n[2] = av1.x; n[3] = av1.y;
        m[0] = bv0.x; m[1] = bv0.y; m[2] = bv1.x; m[3] = bv1.y;
        #pragma unroll
        for (int j = 0; j < 4; ++j) {
            n[4 + j] = __shfl_down(n[j], 1, 64);
            m[4 + j] = __shfl_down(m[j], 1, 64);
        }
        n[8] = __shfl_down(n[0], 2, 64);  n[9] = __shfl_down(n[1], 2, 64);
        m[8] = __shfl_down(m[0], 2, 64);  m[9] = __shfl_down(m[1], 2, 64);

        #pragma unroll
        for (int c = 0; c < 4; ++c) {
            #pragma unroll
            for (int k = 1; k <= NK; ++k) {
                const float d = n[c] - n[c + k];
                s1[c][k - 1] = fmaf(d, d, s1[c][k - 1]);
                s2[c][k - 1] += fabsf(m[c] - m[c + k]);
            }
            const float rr = n[c] - m[c];
            res = fmaf(rr * rr, maskf[c], res);
        }
    }

    // cross-wave reduce: 4 LDS buffers, waves 4..7 add into buffer w-4
    __shared__ float buf[4][QSZ];    // 48 KB
    __shared__ float rw[WPB];
    if (w < 4) {
        #pragma unroll
        for (int k = 0; k < NK; ++k) {
            *reinterpret_cast<float4*>(&buf[w][k * 256 + 4 * l]) =
                make_float4(s1[0][k], s1[1][k], s1[2][k], s1[3][k]);
            *reinterpret_cast<float4*>(&buf[w][NK * 256 + k * 256 + 4 * l]) =
                make_float4(s2[0][k], s2[1][k], s2[2][k], s2[3][k]);
        }
    }
    #pragma unroll
    for (int off = 32; off > 0; off >>= 1) res += __shfl_down(res, off, 64);
    if (l == 0) rw[w] = res;
    __syncthreads();
    if (w >= 4) {
        #pragma unroll
        for (int k = 0; k < NK; ++k) {
            float4* q1 = reinterpret_cast<float4*>(&buf[w - 4][k * 256 + 4 * l]);
            float4 v1 = *q1;
            v1.x += s1[0][k]; v1.y += s1[1][k]; v1.z += s1[2][k]; v1.w += s1[3][k];
            *q1 = v1;
            float4* q2 = reinterpret_cast<float4*>(&buf[w - 4][NK * 256 + k * 256 + 4 * l]);
            float4 v2 = *q2;
            v2.x += s2[0][k]; v2.y += s2[1][k]; v2.z += s2[2][k]; v2.w += s2[3][k];
            *q2 = v2;
        }
    }
    __syncthreads();

    float* pg = p + (size_t)g * SLOTS + (size_t)s * QSZ;
    for (int q = t; q < QSZ; q += NTH1)
        pg[q] = (buf[0][q] + buf[1][q]) + (buf[2][q] + buf[3][q]);
    if (t == 0) {
        float rs = 0.f;
        #pragma unroll
        for (int i = 0; i < WPB; ++i) rs += rw[i];
        resp[blockIdx.x] = rs;
    }
}

// ---------------- K2: final slot sums (no fence, no finish) ----------------
__global__ __launch_bounds__(256) void actloss_k2(
        const float* __restrict__ p, float* __restrict__ fin) {
    const int slot = (int)blockIdx.x * 256 + threadIdx.x;  // always < SLOTS
    float sum = 0.f;
    #pragma unroll 8
    for (int g = 0; g < NGR; ++g) sum += p[(size_t)g * SLOTS + slot];
    fin[slot] = sum;
}

// ---------------- K3: one-block finish ----------------
__global__ __launch_bounds__(256) void actloss_k3(
        const float* __restrict__ fin, const float* __restrict__ resp,
        float* __restrict__ out) {
    const int t = threadIdx.x;
    __shared__ float sm[SLOTS];      // 36 KB
    __shared__ float Tl[NK * TP];    // 18 KB
    for (int q = t; q < SLOTS; q += 256) sm[q] = fin[q];
    __syncthreads();

    // T[k][i] = exp(-0.5*S1)*S2 for valid pairs (i, i+k)
    for (int e = t; e < NSTRIP * NK * 256; e += 256) {   // 4608
        const int s  = e / (NK * 256);
        const int r  = e % (NK * 256);
        const int k1 = r / 256;
        const int q  = r % 256;
        const int i  = s * WSTRIP + q;
        if (q < WSTRIP && i + k1 + 1 <= TLEN - 1) {
            Tl[k1 * TP + i] = expf(-0.5f * sm[s * QSZ + k1 * 256 + q])
                              * sm[s * QSZ + NK * 256 + k1 * 256 + q];
        }
    }
    __syncthreads();

    // map the 8250 (i,j) window terms onto pairs
    float acc = 0.f;
    for (int idx = t; idx < TLEN * 11; idx += 256) {
        const int i = idx / 11, j = idx - i * 11;
        int c = i + j - 6;
        c = c < 0 ? 0 : (c > TLEN - 1 ? TLEN - 1 : c);
        const int k = i < c ? c - i : i - c;
        if (k > 0) acc += Tl[(k - 1) * TP + (i < c ? i : c)];
    }
    float racc = 0.f;
    for (int q = t; q < NSTRIP * NGR; q += 256) racc += resp[q];

    __shared__ float red[4];
    const float accR  = block_reduce<4>(acc, red);
    const float raccR = block_reduce<4>(racc, red);
    if (t == 0) out[0] = (accR + 0.1f * raccR) * (1.0f / (float)BATCH);
}

// ---------------- fallback slow path (round-1, known-good) ----------------

__global__ __launch_bounds__(256) void actloss_col_kernel(
        const float* __restrict__ a, const float* __restrict__ a2,
        float* __restrict__ part) {
    const int i = blockIdx.x;
    const int t = threadIdx.x;
    __shared__ float red[4];
    int cidx[11];
    #pragma unroll
    for (int j = 0; j < 11; ++j) {
        int c = i + j - 6;
        cidx[j] = c < 0 ? 0 : (c > TLEN - 1 ? TLEN - 1 : c);
    }
    float s1[11], s2[11];
    #pragma unroll
    for (int j = 0; j < 11; ++j) { s1[j] = 0.f; s2[j] = 0.f; }
    float resacc = 0.f;
    for (int b = t; b < BATCH; b += 256) {
        const float* arow  = a  + (size_t)b * TLEN;
        const float* a2row = a2 + (size_t)b * TLEN;
        const float ai = arow[i], a2i = a2row[i];
        const float r = ai - a2i;
        resacc = fmaf(r, r, resacc);
        #pragma unroll
        for (int j = 0; j < 11; ++j) {
            const float d = ai - arow[cidx[j]];
            s1[j] = fmaf(d, d, s1[j]);
            s2[j] += fabsf(a2i - a2row[cidx[j]]);
        }
    }
    float term = 0.f;
    #pragma unroll
    for (int j = 0; j < 11; ++j) {
        const float s1r = block_reduce<4>(s1[j], red);
        const float s2r = block_reduce<4>(s2[j], red);
        if (t == 0) term += expf(-0.5f * s1r) * s2r;
    }
    const float resr = block_reduce<4>(resacc, red);
    if (t == 0) part[i] = (term + 0.1f * resr) * (1.0f / (float)BATCH);
}

__global__ __launch_bounds__(256) void actloss_fallback_reduce(
        const float* __restrict__ part, float* __restrict__ out) {
    __shared__ float red[4];
    float v = 0.f;
    for (int k = threadIdx.x; k < TLEN; k += 256) v += part[k];
    const float r = block_reduce<4>(v, red);
    if (threadIdx.x == 0) out[0] = r;
}

// ---------------- launcher ----------------

extern "C" void kernel_launch(void* const* d_in, const int* in_sizes, int n_in,
                              void* d_out, int out_size, void* d_ws, size_t ws_size,
                              hipStream_t stream) {
    const float* a  = (const float*)d_in[0];   // actioness
    const float* a2 = (const float*)d_in[1];   // actioness_2
    float* out = (float*)d_out;
    float* ws  = (float*)d_ws;

    const size_t pN   = (size_t)NGR * SLOTS;          // 1,179,648 floats (4.7 MB)
    const size_t need = (pN + SLOTS + (size_t)NSTRIP * NGR + 16) * sizeof(float);

    if (ws_size >= need) {
        float* p    = ws;
        float* fin  = p + pN;
        float* resp = fin + SLOTS;
        actloss_k1<<<NSTRIP * NGR, NTH1, 0, stream>>>(a, a2, p, resp);
        actloss_k2<<<K2GRID, 256, 0, stream>>>(p, fin);
        actloss_k3<<<1, 256, 0, stream>>>(fin, resp, out);
    } else {
        float* part = ws;   // 750 floats
        actloss_col_kernel<<<TLEN, 256, 0, stream>>>(a, a2, part);
        actloss_fallback_reduce<<<1, 256, 0, stream>>>(part, out);
    }
}

// Round 10
// 26.634 us; speedup vs baseline: 3.1875x; 1.1560x over previous
//
#include <hip/hip_runtime.h>

#define BATCH  4096
#define TLEN   750
#define NK     6                 // pair offsets k=1..6 (k=0 contributes exactly 0)
#define WSTRIP 250               // owned columns per strip
#define NSTRIP 3                 // 3*250 = 750 exactly
#define NTH1   512               // K1 block size (8 waves)
#define WPB    8
#define NGR    128               // row-groups
#define RPB    (BATCH/NGR)       // 32 rows per block
#define RPW    (RPB/WPB)         // 4 rows per wave
#define QSZ    (2*NK*256)        // 3072 floats per (strip,group) partial
#define SLOTS  (NSTRIP*QSZ)      // 9216
#define K2GRID (NSTRIP*NK*2)     // 36 pair-blocks: (strip, k, half)
#define NPB    12                // pair-blocks per strip (NK*2)

// ---------------- helpers ----------------

template<int NW>
__device__ __forceinline__ float block_reduce(float v, float* red) {
    #pragma unroll
    for (int off = 32; off > 0; off >>= 1) v += __shfl_down(v, off, 64);
    const int t = threadIdx.x;
    if ((t & 63) == 0) red[t >> 6] = v;
    __syncthreads();
    float r = 0.f;
    if (t == 0) {
        #pragma unroll
        for (int w = 0; w < NW; ++w) r += red[w];
    }
    __syncthreads();
    return r;
}

// ---------------- K1: strip x row-group pair partials ----------------
// Lane owns 4 columns via two float2 loads (bases even -> 8B aligned; clamp
// keeps in-bounds). Neighborhood n[0..9]: 4 shuffles from lane+1, 2 from
// lane+2 per array. Garbage values reach only slots with q>=250 or i+k>749,
// which K2 provably never consumes.
// Partial layout (pair-blocks): global slot = s*QSZ + (2k+h)*256 + arr*128 + (col&127)
// where col = strip-local column 0..255, h = col>>7, arr: 0=S1, 1=S2.
// So each 256-slot block holds S1 (first 128) and S2 (last 128) of the same
// (strip, k, col-half) -> K2 can finish entirely in-block.
__global__ __launch_bounds__(NTH1, 3) void actloss_k1(
        const float* __restrict__ a, const float* __restrict__ a2,
        float* __restrict__ p, float* __restrict__ resp) {
    const int t = threadIdx.x;
    const int w = t >> 6;
    const int l = t & 63;
    const int s = (int)(blockIdx.x % NSTRIP);
    const int g = (int)(blockIdx.x / NSTRIP);

    const int colr = s * WSTRIP + 4 * l;
    const int bc0  = min(colr,     748);
    const int bc1  = min(colr + 2, 748);

    float maskf[4];
    #pragma unroll
    for (int c = 0; c < 4; ++c) maskf[c] = (4 * l + c < WSTRIP) ? 1.f : 0.f;

    float s1[4][NK], s2[4][NK];
    #pragma unroll
    for (int c = 0; c < 4; ++c)
        #pragma unroll
        for (int k = 0; k < NK; ++k) { s1[c][k] = 0.f; s2[c][k] = 0.f; }
    float res = 0.f;

    const int r0 = g * RPB + w * RPW;
    #pragma unroll
    for (int r = 0; r < RPW; ++r) {
        const size_t off = (size_t)(r0 + r) * TLEN;
        const float2 av0 = *reinterpret_cast<const float2*>(a  + off + bc0);
        const float2 av1 = *reinterpret_cast<const float2*>(a  + off + bc1);
        const float2 bv0 = *reinterpret_cast<const float2*>(a2 + off + bc0);
        const float2 bv1 = *reinterpret_cast<const float2*>(a2 + off + bc1);

        float n[10], m[10];
        n[0] = av0.x; n[1] = av0.y; n[2] = av1.x; n[3] = av1.y;
        m[0] = bv0.x; m[1] = bv0.y; m[2] = bv1.x; m[3] = bv1.y;
        #pragma unroll
        for (int j = 0; j < 4; ++j) {
            n[4 + j] = __shfl_down(n[j], 1, 64);
            m[4 + j] = __shfl_down(m[j], 1, 64);
        }
        n[8] = __shfl_down(n[0], 2, 64);  n[9] = __shfl_down(n[1], 2, 64);
        m[8] = __shfl_down(m[0], 2, 64);  m[9] = __shfl_down(m[1], 2, 64);

        #pragma unroll
        for (int c = 0; c < 4; ++c) {
            #pragma unroll
            for (int k = 1; k <= NK; ++k) {
                const float d = n[c] - n[c + k];
                s1[c][k - 1] = fmaf(d, d, s1[c][k - 1]);
                s2[c][k - 1] += fabsf(m[c] - m[c + k]);
            }
            const float rr = n[c] - m[c];
            res = fmaf(rr * rr, maskf[c], res);
        }
    }

    // cross-wave reduce: 4 LDS buffers, waves 4..7 add into buffer w-4
    __shared__ float buf[4][QSZ];    // 48 KB
    __shared__ float rw[WPB];
    if (w < 4) {
        #pragma unroll
        for (int k = 0; k < NK; ++k) {
            *reinterpret_cast<float4*>(&buf[w][k * 256 + 4 * l]) =
                make_float4(s1[0][k], s1[1][k], s1[2][k], s1[3][k]);
            *reinterpret_cast<float4*>(&buf[w][NK * 256 + k * 256 + 4 * l]) =
                make_float4(s2[0][k], s2[1][k], s2[2][k], s2[3][k]);
        }
    }
    #pragma unroll
    for (int off = 32; off > 0; off >>= 1) res += __shfl_down(res, off, 64);
    if (l == 0) rw[w] = res;
    __syncthreads();
    if (w >= 4) {
        #pragma unroll
        for (int k = 0; k < NK; ++k) {
            float4* q1 = reinterpret_cast<float4*>(&buf[w - 4][k * 256 + 4 * l]);
            float4 v1 = *q1;
            v1.x += s1[0][k]; v1.y += s1[1][k]; v1.z += s1[2][k]; v1.w += s1[3][k];
            *q1 = v1;
            float4* q2 = reinterpret_cast<float4*>(&buf[w - 4][NK * 256 + k * 256 + 4 * l]);
            float4 v2 = *q2;
            v2.x += s2[0][k]; v2.y += s2[1][k]; v2.z += s2[2][k]; v2.w += s2[3][k];
            *q2 = v2;
        }
    }
    __syncthreads();

    // write permuted to pair-block layout (nontemporal: write-once data)
    float* pg = p + (size_t)g * SLOTS + (size_t)s * QSZ;
    for (int q = t; q < QSZ; q += NTH1) {
        const float v = (buf[0][q] + buf[1][q]) + (buf[2][q] + buf[3][q]);
        const int arr = q >= (NK * 256);
        const int rem = q - arr * (NK * 256);
        const int k   = rem >> 8;
        const int col = rem & 255;
        const int idx = ((k << 1) + (col >> 7)) * 256 + arr * 128 + (col & 127);
        __builtin_nontemporal_store(v, &pg[idx]);
    }
    if (t == 0) {
        float rs = 0.f;
        #pragma unroll
        for (int i = 0; i < WPB; ++i) rs += rw[i];
        resp[blockIdx.x] = rs;
    }
}

// ---------------- K2: g-sum + in-block finish -> one scalar per block ----------------
// Block j = (s, k, half). Sums its 256 slots over all 128 groups, then
// T = exp(-S1/2)*S2 and the closed-form window weight:
//   base (k<=4 ? 2 : 1); +(6-k) at i=0; +(4-k) at i=749-k (k<=3).
// Sum of all weights = 7490 = 8250 window terms - 760 identically-zero ones.
__global__ __launch_bounds__(256) void actloss_k2(
        const float* __restrict__ p, float* __restrict__ partial) {
    const int t = threadIdx.x;
    const int j = (int)blockIdx.x;
    __shared__ float sm[256];
    __shared__ float red[4];

    float sum = 0.f;
    const float* base = p + (size_t)j * 256 + t;
    #pragma unroll 8
    for (int g = 0; g < NGR; ++g)
        sum += __builtin_nontemporal_load(&base[(size_t)g * SLOTS]);
    sm[t] = sum;
    __syncthreads();

    float acc = 0.f;
    if (t < 128) {
        const int s  = j / NPB;
        const int jj = j % NPB;
        const int k1 = (jj >> 1) + 1;        // pair offset 1..6
        const int h  = jj & 1;
        const int q  = h * 128 + t;          // strip-local column
        const int i  = s * WSTRIP + q;
        if (q < WSTRIP && i + k1 <= TLEN - 1) {
            const float Tv = expf(-0.5f * sm[t]) * sm[t + 128];
            float wgt = (k1 <= 4) ? 2.f : 1.f;
            if (i == 0) wgt += (float)(6 - k1);
            if (k1 <= 3 && i == TLEN - 1 - k1) wgt += (float)(4 - k1);
            acc = wgt * Tv;
        }
    }
    const float r = block_reduce<4>(acc, red);
    if (t == 0) partial[j] = r;
}

// ---------------- K3: trivial scalar finish ----------------
__global__ __launch_bounds__(256) void actloss_k3(
        const float* __restrict__ partial, const float* __restrict__ resp,
        float* __restrict__ out) {
    const int t = threadIdx.x;
    __shared__ float red[4];
    float pa = (t < K2GRID) ? partial[t] : 0.f;
    float ra = 0.f;
    for (int q = t; q < NSTRIP * NGR; q += 256) ra += resp[q];
    const float paR = block_reduce<4>(pa, red);
    const float raR = block_reduce<4>(ra, red);
    if (t == 0) out[0] = (paR + 0.1f * raR) * (1.0f / (float)BATCH);
}

// ---------------- fallback slow path (round-1, known-good) ----------------

__global__ __launch_bounds__(256) void actloss_col_kernel(
        const float* __restrict__ a, const float* __restrict__ a2,
        float* __restrict__ part) {
    const int i = blockIdx.x;
    const int t = threadIdx.x;
    __shared__ float red[4];
    int cidx[11];
    #pragma unroll
    for (int j = 0; j < 11; ++j) {
        int c = i + j - 6;
        cidx[j] = c < 0 ? 0 : (c > TLEN - 1 ? TLEN - 1 : c);
    }
    float s1[11], s2[11];
    #pragma unroll
    for (int j = 0; j < 11; ++j) { s1[j] = 0.f; s2[j] = 0.f; }
    float resacc = 0.f;
    for (int b = t; b < BATCH; b += 256) {
        const float* arow  = a  + (size_t)b * TLEN;
        const float* a2row = a2 + (size_t)b * TLEN;
        const float ai = arow[i], a2i = a2row[i];
        const float r = ai - a2i;
        resacc = fmaf(r, r, resacc);
        #pragma unroll
        for (int j = 0; j < 11; ++j) {
            const float d = ai - arow[cidx[j]];
            s1[j] = fmaf(d, d, s1[j]);
            s2[j] += fabsf(a2i - a2row[cidx[j]]);
        }
    }
    float term = 0.f;
    #pragma unroll
    for (int j = 0; j < 11; ++j) {
        const float s1r = block_reduce<4>(s1[j], red);
        const float s2r = block_reduce<4>(s2[j], red);
        if (t == 0) term += expf(-0.5f * s1r) * s2r;
    }
    const float resr = block_reduce<4>(resacc, red);
    if (t == 0) part[i] = (term + 0.1f * resr) * (1.0f / (float)BATCH);
}

__global__ __launch_bounds__(256) void actloss_fallback_reduce(
        const float* __restrict__ part, float* __restrict__ out) {
    __shared__ float red[4];
    float v = 0.f;
    for (int k = threadIdx.x; k < TLEN; k += 256) v += part[k];
    const float r = block_reduce<4>(v, red);
    if (threadIdx.x == 0) out[0] = r;
}

// ---------------- launcher ----------------

extern "C" void kernel_launch(void* const* d_in, const int* in_sizes, int n_in,
                              void* d_out, int out_size, void* d_ws, size_t ws_size,
                              hipStream_t stream) {
    const float* a  = (const float*)d_in[0];   // actioness
    const float* a2 = (const float*)d_in[1];   // actioness_2
    float* out = (float*)d_out;
    float* ws  = (float*)d_ws;

    const size_t pN   = (size_t)NGR * SLOTS;          // 1,179,648 floats (4.7 MB)
    const size_t need = (pN + 64 + (size_t)NSTRIP * NGR + 16) * sizeof(float);

    if (ws_size >= need) {
        float* p       = ws;
        float* partial = p + pN;            // 36 (padded to 64)
        float* resp    = partial + 64;      // 384
        actloss_k1<<<NSTRIP * NGR, NTH1, 0, stream>>>(a, a2, p, resp);
        actloss_k2<<<K2GRID, 256, 0, stream>>>(p, partial);
        actloss_k3<<<1, 256, 0, stream>>>(partial, resp, out);
    } else {
        float* part = ws;   // 750 floats
        actloss_col_kernel<<<TLEN, 256, 0, stream>>>(a, a2, part);
        actloss_fallback_reduce<<<1, 256, 0, stream>>>(part, out);
    }
}

// Round 11
// 22.878 us; speedup vs baseline: 3.7109x; 1.1642x over previous
//
#include <hip/hip_runtime.h>

#define BATCH  4096
#define TLEN   750
#define NK     6                 // pair offsets k=1..6 (k=0 contributes exactly 0)
#define WSTRIP 250               // owned columns per strip
#define NSTRIP 3                 // 3*250 = 750 exactly
#define NTH1   768               // 12 waves = 3 strips x 4 row-subsets
#define RSUB   4                 // row-subsets per block
#define NGR    256               // row-groups == K1 grid (1 block/CU, balanced)
#define RPB    (BATCH/NGR)       // 16 rows per block
#define RPW    (RPB/RSUB)        // 4 rows per wave
#define QSZ    (2*NK*256)        // 3072 floats per strip partial
#define NJ     (NSTRIP*NK*2)     // 36 pair-blocks (strip, k, half)
#define NTH2   1024              // K2 block size

// ---------------- helpers ----------------

template<int NW>
__device__ __forceinline__ float block_reduce(float v, float* red) {
    #pragma unroll
    for (int off = 32; off > 0; off >>= 1) v += __shfl_down(v, off, 64);
    const int t = threadIdx.x;
    if ((t & 63) == 0) red[t >> 6] = v;
    __syncthreads();
    float r = 0.f;
    if (t == 0) {
        #pragma unroll
        for (int w = 0; w < NW; ++w) r += red[w];
    }
    __syncthreads();
    return r;
}

// ---------------- K1: one balanced block per row-group ----------------
// Wave w: strip s = w%3, row-subset rw = w/3 (4 rows each). Lane owns 4 cols
// via two float2 loads (even bases -> 8B aligned; min(...,748) clamps at the
// array end). Neighborhood n[0..9]: 4 shuffles from lane+1, 2 from lane+2.
// Garbage reaches only slots with strip-local q>=250 or i+k>749 -- K2 skips.
// Partials land TRANSPOSED: p[j][g][idx], j=(s*12+2k+h), so K2 streams.
__global__ __launch_bounds__(NTH1, 3) void actloss_k1(
        const float* __restrict__ a, const float* __restrict__ a2,
        float* __restrict__ p, float* __restrict__ resp) {
    const int t  = threadIdx.x;
    const int w  = t >> 6;
    const int l  = t & 63;
    const int s  = w % NSTRIP;
    const int rw = w / NSTRIP;
    const int g  = (int)blockIdx.x;

    const int colr = s * WSTRIP + 4 * l;
    const int bc0  = min(colr,     TLEN - 2);
    const int bc1  = min(colr + 2, TLEN - 2);

    float maskf[4];
    #pragma unroll
    for (int c = 0; c < 4; ++c) maskf[c] = (4 * l + c < WSTRIP) ? 1.f : 0.f;

    float s1[4][NK], s2[4][NK];
    #pragma unroll
    for (int c = 0; c < 4; ++c)
        #pragma unroll
        for (int k = 0; k < NK; ++k) { s1[c][k] = 0.f; s2[c][k] = 0.f; }
    float res = 0.f;

    const int r0 = g * RPB + rw * RPW;
    #pragma unroll
    for (int r = 0; r < RPW; ++r) {
        const size_t off = (size_t)(r0 + r) * TLEN;
        const float2 av0 = *reinterpret_cast<const float2*>(a  + off + bc0);
        const float2 av1 = *reinterpret_cast<const float2*>(a  + off + bc1);
        const float2 bv0 = *reinterpret_cast<const float2*>(a2 + off + bc0);
        const float2 bv1 = *reinterpret_cast<const float2*>(a2 + off + bc1);

        float n[10], m[10];
        n[0] = av0.x; n[1] = av0.y; n[2] = av1.x; n[3] = av1.y;
        m[0] = bv0.x; m[1] = bv0.y; m[2] = bv1.x; m[3] = bv1.y;
        #pragma unroll
        for (int j = 0; j < 4; ++j) {
            n[4 + j] = __shfl_down(n[j], 1, 64);
            m[4 + j] = __shfl_down(m[j], 1, 64);
        }
        n[8] = __shfl_down(n[0], 2, 64);  n[9] = __shfl_down(n[1], 2, 64);
        m[8] = __shfl_down(m[0], 2, 64);  m[9] = __shfl_down(m[1], 2, 64);

        #pragma unroll
        for (int c = 0; c < 4; ++c) {
            #pragma unroll
            for (int k = 1; k <= NK; ++k) {
                const float d = n[c] - n[c + k];
                s1[c][k - 1] = fmaf(d, d, s1[c][k - 1]);
                s2[c][k - 1] += fabsf(m[c] - m[c + k]);
            }
            const float rr = n[c] - m[c];
            res = fmaf(rr * rr, maskf[c], res);
        }
    }

    // staged cross-subset reduce: rw==0 writes, rw==1..3 add (barrier-phased)
    __shared__ float buf[NSTRIP][QSZ];    // 36 KB
    __shared__ float rwred[12];
    if (rw == 0) {
        #pragma unroll
        for (int k = 0; k < NK; ++k) {
            *reinterpret_cast<float4*>(&buf[s][k * 256 + 4 * l]) =
                make_float4(s1[0][k], s1[1][k], s1[2][k], s1[3][k]);
            *reinterpret_cast<float4*>(&buf[s][NK * 256 + k * 256 + 4 * l]) =
                make_float4(s2[0][k], s2[1][k], s2[2][k], s2[3][k]);
        }
    }
    #pragma unroll
    for (int off = 32; off > 0; off >>= 1) res += __shfl_down(res, off, 64);
    if (l == 0) rwred[w] = res;
    __syncthreads();
    #pragma unroll
    for (int stage = 1; stage < RSUB; ++stage) {
        if (rw == stage) {
            #pragma unroll
            for (int k = 0; k < NK; ++k) {
                float4* q1 = reinterpret_cast<float4*>(&buf[s][k * 256 + 4 * l]);
                float4 v1 = *q1;
                v1.x += s1[0][k]; v1.y += s1[1][k]; v1.z += s1[2][k]; v1.w += s1[3][k];
                *q1 = v1;
                float4* q2 = reinterpret_cast<float4*>(&buf[s][NK * 256 + k * 256 + 4 * l]);
                float4 v2 = *q2;
                v2.x += s2[0][k]; v2.y += s2[1][k]; v2.z += s2[2][k]; v2.w += s2[3][k];
                *q2 = v2;
            }
        }
        __syncthreads();
    }

    // store transposed: p[((s*12 + 2k + h)*NGR + g)*256 + idx]
    for (int q = t; q < NSTRIP * QSZ; q += NTH1) {   // 12 iters
        const int si  = q / QSZ;
        const int qq  = q % QSZ;
        const float v = buf[si][qq];
        const int arr = qq >= (NK * 256);
        const int rem = qq - arr * (NK * 256);
        const int k   = rem >> 8;
        const int col = rem & 255;
        const int h   = col >> 7;
        const int idx = (col & 127) + arr * 128;
        const int j   = si * 12 + (k << 1) + h;
        p[((size_t)j * NGR + g) * 256 + idx] = v;
    }
    if (t == 0) {
        float rs = 0.f;
        #pragma unroll
        for (int i = 0; i < 12; ++i) rs += rwred[i];
        resp[g] = rs;
    }
}

// ---------------- K2: streaming g-sum + in-block finish ----------------
// Block j streams its contiguous 256 KB slab p[j][0..NGR*256) with float4,
// reduces 16 wave-partials in LDS, applies exp + closed-form window weight:
//   base (k<=4 ? 2 : 1); +(6-k) at i=0; +(4-k) at i=749-k (k<=3).
__global__ __launch_bounds__(NTH2) void actloss_k2(
        const float* __restrict__ p, float* __restrict__ partial) {
    const int t = threadIdx.x;
    const int j = (int)blockIdx.x;
    const float4* slab = reinterpret_cast<const float4*>(p + (size_t)j * NGR * 256);

    float4 acc4 = make_float4(0.f, 0.f, 0.f, 0.f);
    #pragma unroll
    for (int pass = 0; pass < NGR / 16; ++pass) {      // 16 passes
        const float4 v = slab[pass * 1024 + t];        // fully coalesced stream
        acc4.x += v.x; acc4.y += v.y; acc4.z += v.z; acc4.w += v.w;
    }

    __shared__ float buf[16][256];   // 16 KB
    __shared__ float sm[256];
    __shared__ float red[16];
    const int w  = t >> 6;
    const int sl = 4 * (t & 63);
    *reinterpret_cast<float4*>(&buf[w][sl]) = acc4;
    __syncthreads();
    if (t < 256) {
        float v = 0.f;
        #pragma unroll
        for (int w2 = 0; w2 < 16; ++w2) v += buf[w2][t];
        sm[t] = v;
    }
    __syncthreads();

    float acc = 0.f;
    if (t < 128) {
        const int s  = j / 12;
        const int jj = j % 12;
        const int k1 = (jj >> 1) + 1;
        const int h  = jj & 1;
        const int col = h * 128 + t;
        const int i   = s * WSTRIP + col;
        if (col < WSTRIP && i + k1 <= TLEN - 1) {
            const float Tv = expf(-0.5f * sm[t]) * sm[t + 128];
            float wgt = (k1 <= 4) ? 2.f : 1.f;
            if (i == 0) wgt += (float)(6 - k1);
            if (k1 <= 3 && i == TLEN - 1 - k1) wgt += (float)(4 - k1);
            acc = wgt * Tv;
        }
    }
    const float r = block_reduce<16>(acc, red);
    if (t == 0) partial[j] = r;
}

// ---------------- K3: trivial scalar finish ----------------
__global__ __launch_bounds__(256) void actloss_k3(
        const float* __restrict__ partial, const float* __restrict__ resp,
        float* __restrict__ out) {
    const int t = threadIdx.x;
    __shared__ float red[4];
    const float pa = (t < NJ) ? partial[t] : 0.f;
    const float ra = resp[t];                 // NGR == 256 == block size
    const float paR = block_reduce<4>(pa, red);
    const float raR = block_reduce<4>(ra, red);
    if (t == 0) out[0] = (paR + 0.1f * raR) * (1.0f / (float)BATCH);
}

// ---------------- fallback slow path (round-1, known-good) ----------------

__global__ __launch_bounds__(256) void actloss_col_kernel(
        const float* __restrict__ a, const float* __restrict__ a2,
        float* __restrict__ part) {
    const int i = blockIdx.x;
    const int t = threadIdx.x;
    __shared__ float red[4];
    int cidx[11];
    #pragma unroll
    for (int j = 0; j < 11; ++j) {
        int c = i + j - 6;
        cidx[j] = c < 0 ? 0 : (c > TLEN - 1 ? TLEN - 1 : c);
    }
    float s1[11], s2[11];
    #pragma unroll
    for (int j = 0; j < 11; ++j) { s1[j] = 0.f; s2[j] = 0.f; }
    float resacc = 0.f;
    for (int b = t; b < BATCH; b += 256) {
        const float* arow  = a  + (size_t)b * TLEN;
        const float* a2row = a2 + (size_t)b * TLEN;
        const float ai = arow[i], a2i = a2row[i];
        const float r = ai - a2i;
        resacc = fmaf(r, r, resacc);
        #pragma unroll
        for (int j = 0; j < 11; ++j) {
            const float d = ai - arow[cidx[j]];
            s1[j] = fmaf(d, d, s1[j]);
            s2[j] += fabsf(a2i - a2row[cidx[j]]);
        }
    }
    float term = 0.f;
    #pragma unroll
    for (int j = 0; j < 11; ++j) {
        const float s1r = block_reduce<4>(s1[j], red);
        const float s2r = block_reduce<4>(s2[j], red);
        if (t == 0) term += expf(-0.5f * s1r) * s2r;
    }
    const float resr = block_reduce<4>(resacc, red);
    if (t == 0) part[i] = (term + 0.1f * resr) * (1.0f / (float)BATCH);
}

__global__ __launch_bounds__(256) void actloss_fallback_reduce(
        const float* __restrict__ part, float* __restrict__ out) {
    __shared__ float red[4];
    float v = 0.f;
    for (int k = threadIdx.x; k < TLEN; k += 256) v += part[k];
    const float r = block_reduce<4>(v, red);
    if (threadIdx.x == 0) out[0] = r;
}

// ---------------- launcher ----------------

extern "C" void kernel_launch(void* const* d_in, const int* in_sizes, int n_in,
                              void* d_out, int out_size, void* d_ws, size_t ws_size,
                              hipStream_t stream) {
    const float* a  = (const float*)d_in[0];   // actioness
    const float* a2 = (const float*)d_in[1];   // actioness_2
    float* out = (float*)d_out;
    float* ws  = (float*)d_ws;

    const size_t pN   = (size_t)NJ * NGR * 256;       // 2,359,296 floats (9.4 MB)
    const size_t need = (pN + 64 + NGR + 16) * sizeof(float);

    if (ws_size >= need) {
        float* p       = ws;
        float* partial = p + pN;            // 36 (padded to 64)
        float* resp    = partial + 64;      // 256
        actloss_k1<<<NGR,  NTH1, 0, stream>>>(a, a2, p, resp);
        actloss_k2<<<NJ,   NTH2, 0, stream>>>(p, partial);
        actloss_k3<<<1,    256,  0, stream>>>(partial, resp, out);
    } else {
        float* part = ws;   // 750 floats
        actloss_col_kernel<<<TLEN, 256, 0, stream>>>(a, a2, part);
        actloss_fallback_reduce<<<1, 256, 0, stream>>>(part, out);
    }
}

// Round 12
// 19.547 us; speedup vs baseline: 4.3432x; 1.1704x over previous
//
#include <hip/hip_runtime.h>

#define BATCH  4096
#define TLEN   750
#define NK     6                 // pair offsets k=1..6 (k=0 contributes exactly 0)
#define WSTRIP 250               // owned columns per strip
#define NSTRIP 3                 // 3*250 = 750 exactly
#define NTH1   768               // 12 waves = 3 strips x 4 row-subsets
#define RSUB   4                 // row-subsets per block
#define NGR    256               // row-groups == K1 grid (1 block/CU, balanced)
#define RPB    (BATCH/NGR)       // 16 rows per block
#define RPW    (RPB/RSUB)        // 4 rows per wave
#define QSZ    (2*NK*256)        // 3072 floats per strip partial (LDS)
#define NJ     (NSTRIP*NK*2)     // 36 pair-slabs (strip, k, half)
#define NTH2   1024              // K2 block size

// ---------------- helpers ----------------

template<int NW>
__device__ __forceinline__ float block_reduce(float v, float* red) {
    #pragma unroll
    for (int off = 32; off > 0; off >>= 1) v += __shfl_down(v, off, 64);
    const int t = threadIdx.x;
    if ((t & 63) == 0) red[t >> 6] = v;
    __syncthreads();
    float r = 0.f;
    if (t == 0) {
        #pragma unroll
        for (int w = 0; w < NW; ++w) r += red[w];
    }
    __syncthreads();
    return r;
}

// pack two non-negative finite floats as bf16 pair (RNE-ish) into one u32
__device__ __forceinline__ unsigned pack2(float v1, float v2) {
    const unsigned b1 = (__float_as_uint(v1) + 0x8000u) >> 16;
    const unsigned b2 = (__float_as_uint(v2) + 0x8000u) >> 16;
    return (b1 << 16) | (b2 & 0xffffu);
}

// ---------------- K1: one balanced block per row-group ----------------
// Wave w: strip s = w%3, row-subset rw = w/3 (4 rows). Lane owns 4 cols via
// two float2 loads (even bases -> 8B aligned; min(...,748) clamps at array
// end). ALL 16 loads of the 4-row batch are issued before any dependent op.
// Neighborhood n[0..9]: 4 shuffles from lane+1, 2 from lane+2 per array.
// Garbage reaches only slots with strip-local q>=250 or i+k>749 -- K2 gates.
// Partials stored TRANSPOSED + bf16-PACKED: pu[((s*12+2k+h)*NGR+g)*128 + idx],
// u32 = (bf16(S1)<<16)|bf16(S2), h=col>>7, idx=col&127.
__global__ __launch_bounds__(NTH1, 3) void actloss_k1(
        const float* __restrict__ a, const float* __restrict__ a2,
        unsigned* __restrict__ pu, float* __restrict__ resp) {
    const int t  = threadIdx.x;
    const int w  = t >> 6;
    const int l  = t & 63;
    const int s  = w % NSTRIP;
    const int rw = w / NSTRIP;
    const int g  = (int)blockIdx.x;

    const int colr = s * WSTRIP + 4 * l;
    const int bc0  = min(colr,     TLEN - 2);
    const int bc1  = min(colr + 2, TLEN - 2);

    float maskf[4];
    #pragma unroll
    for (int c = 0; c < 4; ++c) maskf[c] = (4 * l + c < WSTRIP) ? 1.f : 0.f;

    float s1[4][NK], s2[4][NK];
    #pragma unroll
    for (int c = 0; c < 4; ++c)
        #pragma unroll
        for (int k = 0; k < NK; ++k) { s1[c][k] = 0.f; s2[c][k] = 0.f; }
    float res = 0.f;

    const int r0 = g * RPB + rw * RPW;

    // ---- issue ALL loads of the 4-row batch up front (16 float2 in flight) --
    float2 A0[RPW], A1[RPW], B0[RPW], B1[RPW];
    #pragma unroll
    for (int r = 0; r < RPW; ++r) {
        const size_t off = (size_t)(r0 + r) * TLEN;
        A0[r] = *reinterpret_cast<const float2*>(a  + off + bc0);
        A1[r] = *reinterpret_cast<const float2*>(a  + off + bc1);
        B0[r] = *reinterpret_cast<const float2*>(a2 + off + bc0);
        B1[r] = *reinterpret_cast<const float2*>(a2 + off + bc1);
    }

    #pragma unroll
    for (int r = 0; r < RPW; ++r) {
        float n[10], m[10];
        n[0] = A0[r].x; n[1] = A0[r].y; n[2] = A1[r].x; n[3] = A1[r].y;
        m[0] = B0[r].x; m[1] = B0[r].y; m[2] = B1[r].x; m[3] = B1[r].y;
        #pragma unroll
        for (int j = 0; j < 4; ++j) {
            n[4 + j] = __shfl_down(n[j], 1, 64);
            m[4 + j] = __shfl_down(m[j], 1, 64);
        }
        n[8] = __shfl_down(n[0], 2, 64);  n[9] = __shfl_down(n[1], 2, 64);
        m[8] = __shfl_down(m[0], 2, 64);  m[9] = __shfl_down(m[1], 2, 64);

        #pragma unroll
        for (int c = 0; c < 4; ++c) {
            #pragma unroll
            for (int k = 1; k <= NK; ++k) {
                const float d = n[c] - n[c + k];
                s1[c][k - 1] = fmaf(d, d, s1[c][k - 1]);
                s2[c][k - 1] += fabsf(m[c] - m[c + k]);
            }
            const float rr = n[c] - m[c];
            res = fmaf(rr * rr, maskf[c], res);
        }
    }

    // staged cross-subset reduce: rw==0 writes, rw==1..3 add (barrier-phased)
    __shared__ float buf[NSTRIP][QSZ];    // 36 KB
    __shared__ float rwred[12];
    if (rw == 0) {
        #pragma unroll
        for (int k = 0; k < NK; ++k) {
            *reinterpret_cast<float4*>(&buf[s][k * 256 + 4 * l]) =
                make_float4(s1[0][k], s1[1][k], s1[2][k], s1[3][k]);
            *reinterpret_cast<float4*>(&buf[s][NK * 256 + k * 256 + 4 * l]) =
                make_float4(s2[0][k], s2[1][k], s2[2][k], s2[3][k]);
        }
    }
    #pragma unroll
    for (int off = 32; off > 0; off >>= 1) res += __shfl_down(res, off, 64);
    if (l == 0) rwred[w] = res;
    __syncthreads();
    #pragma unroll
    for (int stage = 1; stage < RSUB; ++stage) {
        if (rw == stage) {
            #pragma unroll
            for (int k = 0; k < NK; ++k) {
                float4* q1 = reinterpret_cast<float4*>(&buf[s][k * 256 + 4 * l]);
                float4 v1 = *q1;
                v1.x += s1[0][k]; v1.y += s1[1][k]; v1.z += s1[2][k]; v1.w += s1[3][k];
                *q1 = v1;
                float4* q2 = reinterpret_cast<float4*>(&buf[s][NK * 256 + k * 256 + 4 * l]);
                float4 v2 = *q2;
                v2.x += s2[0][k]; v2.y += s2[1][k]; v2.z += s2[2][k]; v2.w += s2[3][k];
                *q2 = v2;
            }
        }
        __syncthreads();
    }

    // packed transposed store: 4608 u32 per block, 6 iterations
    for (int e = t; e < NSTRIP * NK * 256; e += NTH1) {
        const int si  = e / (NK * 256);
        const int rem = e % (NK * 256);
        const int k   = rem >> 8;
        const int col = rem & 255;
        const int h   = col >> 7;
        const int idx = col & 127;
        const unsigned pk = pack2(buf[si][k * 256 + col],
                                  buf[si][NK * 256 + k * 256 + col]);
        pu[((size_t)(si * 12 + (k << 1) + h) * NGR + g) * 128 + idx] = pk;
    }
    if (t == 0) {
        float rs = 0.f;
        #pragma unroll
        for (int i = 0; i < 12; ++i) rs += rwred[i];
        resp[g] = rs;
    }
}

// ---------------- K2: streaming packed g-sum + in-block finish ----------------
// Block j streams its contiguous 128 KB slab with uint4, unpacks bf16 pairs,
// accumulates f32, transposes via LDS, applies exp + closed-form weight:
//   base (k<=4 ? 2 : 1); +(6-k) at i=0; +(4-k) at i=749-k (k<=3).
// Block 0 additionally reduces the res partials into partial[36].
__global__ __launch_bounds__(NTH2) void actloss_k2(
        const unsigned* __restrict__ pu, const float* __restrict__ resp,
        float* __restrict__ partial) {
    const int t = threadIdx.x;
    const int j = (int)blockIdx.x;
    const uint4* slab = reinterpret_cast<const uint4*>(pu + (size_t)j * NGR * 128);

    const int cg    = t & 31;    // colgroup: cols 4cg..4cg+3
    const int gbase = t >> 5;    // 0..31

    float s1a[4] = {0.f, 0.f, 0.f, 0.f}, s2a[4] = {0.f, 0.f, 0.f, 0.f};
    #pragma unroll
    for (int pass = 0; pass < NGR / 32; ++pass) {          // 8 passes
        const uint4 v = slab[(size_t)(pass * 32 + gbase) * 32 + cg];
        const unsigned u[4] = {v.x, v.y, v.z, v.w};
        #pragma unroll
        for (int c = 0; c < 4; ++c) {
            s1a[c] += __uint_as_float(u[c] & 0xffff0000u);
            s2a[c] += __uint_as_float(u[c] << 16);
        }
    }

    __shared__ float smA[NTH2][5], smB[NTH2][5];   // pad 5: conflict-free writes
    __shared__ float red[16];
    #pragma unroll
    for (int c = 0; c < 4; ++c) { smA[t][c] = s1a[c]; smB[t][c] = s2a[c]; }
    __syncthreads();

    float acc = 0.f;
    if (t < 128) {
        float S1 = 0.f, S2 = 0.f;
        const int rcg = t >> 2, ci = t & 3;
        #pragma unroll
        for (int q = 0; q < 32; ++q) {
            S1 += smA[q * 32 + rcg][ci];
            S2 += smB[q * 32 + rcg][ci];
        }
        const int s  = j / 12;
        const int jj = j % 12;
        const int k1 = (jj >> 1) + 1;
        const int h  = jj & 1;
        const int col = h * 128 + t;
        const int i   = s * WSTRIP + col;
        if (col < WSTRIP && i + k1 <= TLEN - 1) {
            const float Tv = expf(-0.5f * S1) * S2;
            float wgt = (k1 <= 4) ? 2.f : 1.f;
            if (i == 0) wgt += (float)(6 - k1);
            if (k1 <= 3 && i == TLEN - 1 - k1) wgt += (float)(4 - k1);
            acc = wgt * Tv;
        }
    }
    const float r = block_reduce<16>(acc, red);
    if (t == 0) partial[j] = r;

    if (j == 0) {   // block-uniform: fold res reduction into K2
        const float ra = (t < NGR) ? resp[t] : 0.f;
        const float r2 = block_reduce<16>(ra, red);
        if (t == 0) partial[NJ] = r2;
    }
}

// ---------------- K3: single-wave scalar finish ----------------
__global__ __launch_bounds__(64) void actloss_k3(
        const float* __restrict__ partial, float* __restrict__ out) {
    const int t = threadIdx.x;
    float v = (t < NJ) ? partial[t] : 0.f;
    if (t == 0) v += 0.1f * partial[NJ];
    #pragma unroll
    for (int off = 32; off > 0; off >>= 1) v += __shfl_down(v, off, 64);
    if (t == 0) out[0] = v * (1.0f / (float)BATCH);
}

// ---------------- fallback slow path (round-1, known-good) ----------------

__global__ __launch_bounds__(256) void actloss_col_kernel(
        const float* __restrict__ a, const float* __restrict__ a2,
        float* __restrict__ part) {
    const int i = blockIdx.x;
    const int t = threadIdx.x;
    __shared__ float red[4];
    int cidx[11];
    #pragma unroll
    for (int j = 0; j < 11; ++j) {
        int c = i + j - 6;
        cidx[j] = c < 0 ? 0 : (c > TLEN - 1 ? TLEN - 1 : c);
    }
    float s1[11], s2[11];
    #pragma unroll
    for (int j = 0; j < 11; ++j) { s1[j] = 0.f; s2[j] = 0.f; }
    float resacc = 0.f;
    for (int b = t; b < BATCH; b += 256) {
        const float* arow  = a  + (size_t)b * TLEN;
        const float* a2row = a2 + (size_t)b * TLEN;
        const float ai = arow[i], a2i = a2row[i];
        const float r = ai - a2i;
        resacc = fmaf(r, r, resacc);
        #pragma unroll
        for (int j = 0; j < 11; ++j) {
            const float d = ai - arow[cidx[j]];
            s1[j] = fmaf(d, d, s1[j]);
            s2[j] += fabsf(a2i - a2row[cidx[j]]);
        }
    }
    float term = 0.f;
    #pragma unroll
    for (int j = 0; j < 11; ++j) {
        const float s1r = block_reduce<4>(s1[j], red);
        const float s2r = block_reduce<4>(s2[j], red);
        if (t == 0) term += expf(-0.5f * s1r) * s2r;
    }
    const float resr = block_reduce<4>(resacc, red);
    if (t == 0) part[i] = (term + 0.1f * resr) * (1.0f / (float)BATCH);
}

__global__ __launch_bounds__(256) void actloss_fallback_reduce(
        const float* __restrict__ part, float* __restrict__ out) {
    __shared__ float red[4];
    float v = 0.f;
    for (int k = threadIdx.x; k < TLEN; k += 256) v += part[k];
    const float r = block_reduce<4>(v, red);
    if (threadIdx.x == 0) out[0] = r;
}

// ---------------- launcher ----------------

extern "C" void kernel_launch(void* const* d_in, const int* in_sizes, int n_in,
                              void* d_out, int out_size, void* d_ws, size_t ws_size,
                              hipStream_t stream) {
    const float* a  = (const float*)d_in[0];   // actioness
    const float* a2 = (const float*)d_in[1];   // actioness_2
    float* out = (float*)d_out;

    const size_t puN  = (size_t)NJ * NGR * 128;       // 1,179,648 u32 (4.7 MB)
    const size_t need = (puN + 64 + NGR + 16) * 4;

    if (ws_size >= need) {
        unsigned* pu      = (unsigned*)d_ws;
        float*    partial = (float*)(pu + puN);   // 37 (padded to 64)
        float*    resp    = partial + 64;         // 256
        actloss_k1<<<NGR, NTH1, 0, stream>>>(a, a2, pu, resp);
        actloss_k2<<<NJ,  NTH2, 0, stream>>>(pu, resp, partial);
        actloss_k3<<<1,   64,   0, stream>>>(partial, out);
    } else {
        float* part = (float*)d_ws;   // 750 floats
        actloss_col_kernel<<<TLEN, 256, 0, stream>>>(a, a2, part);
        actloss_fallback_reduce<<<1, 256, 0, stream>>>(part, out);
    }
}